// Round 8
// baseline (473.490 us; speedup 1.0000x reference)
//
#include <hip/hip_runtime.h>
#include <stdint.h>

#define BATCH 256
#define CIN   64
#define LIN   4096
#define PADN  3
#define LPAD  4102            /* 4096 + 2*3 */
#define COUT  128
#define KW    7
#define LPOOL 2048
#define NBUCKET 64
#define NPERCH (256LL * 2048LL)

typedef unsigned long long u64;
typedef __attribute__((ext_vector_type(4)))  int i32x4;
typedef __attribute__((ext_vector_type(16))) int i32x16;
typedef __attribute__((ext_vector_type(8)))  short s16x8;

#define ACC_ZERO {0,0,0,0,0,0,0,0,0,0,0,0,0,0,0,0}

static __device__ __forceinline__ int pk16(int a, int b)
{
    return (a & 0xFFFF) | (b << 16);   // low short = first value
}

// ---------------------------------------------------------------------------
// pack_x: x[b][c][l] fp32 -> sx[b_local][l+3][c] i8 sign (+1/-1/0).
// Pad rows (0..2, 4099..4101) = -1 (sign of pad value -1.0).  [R3-proven]
// ---------------------------------------------------------------------------
__global__ __launch_bounds__(256) void pack_x_kernel(const float* __restrict__ x,
                                                     char* __restrict__ sx,
                                                     int b_base)
{
    const int t  = threadIdx.x;
    const int lt = blockIdx.x;            // 16 tiles of 256 positions
    const int bl = blockIdx.y;            // local batch index in chunk
    const int b  = b_base + bl;
    const int l  = lt * 256 + t;
    const float* xb = x + (size_t)b * CIN * LIN + l;

    int o[16];
    #pragma unroll
    for (int cw = 0; cw < 16; ++cw) {
        unsigned wv = 0;
        #pragma unroll
        for (int j = 0; j < 4; ++j) {
            float v = xb[(size_t)(cw * 4 + j) * LIN];
            unsigned s = (v > 0.0f) ? 1u : ((v < 0.0f) ? 0xFFu : 0u);
            wv |= s << (8 * j);
        }
        o[cw] = (int)wv;
    }
    i32x4* dst = (i32x4*)(sx + ((size_t)bl * LPAD + (l + PADN)) * 64);
    dst[0] = (i32x4){o[0],  o[1],  o[2],  o[3]};
    dst[1] = (i32x4){o[4],  o[5],  o[6],  o[7]};
    dst[2] = (i32x4){o[8],  o[9],  o[10], o[11]};
    dst[3] = (i32x4){o[12], o[13], o[14], o[15]};

    const i32x4 ff = (i32x4){-1, -1, -1, -1};   // bytes 0xFF = sign(-1)
    if (lt == 0 && t < PADN) {
        i32x4* pd = (i32x4*)(sx + ((size_t)bl * LPAD + t) * 64);
        pd[0] = ff; pd[1] = ff; pd[2] = ff; pd[3] = ff;
    }
    if (lt == 15 && t < PADN) {
        i32x4* pd = (i32x4*)(sx + ((size_t)bl * LPAD + (LIN + PADN) + t) * 64);
        pd[0] = ff; pd[1] = ff; pd[2] = ff; pd[3] = ff;
    }
}

// ---------------------------------------------------------------------------
// pack_w: W[co][c][kk] fp32 -> pwb[kk][co][c] i8 sign.  [R3-proven]
// ---------------------------------------------------------------------------
__global__ __launch_bounds__(256) void pack_w_kernel(const float* __restrict__ w,
                                                     char* __restrict__ pwb)
{
    int idx = blockIdx.x * 256 + threadIdx.x;     // [0, 7*128*64)
    if (idx >= KW * COUT * CIN) return;
    int kk = idx >> 13;
    int co = (idx >> 6) & 127;
    int c  = idx & 63;
    float v = w[((size_t)co * CIN + c) * KW + kk];
    pwb[idx] = (char)((v > 0.0f) ? 1 : ((v < 0.0f) ? -1 : 0));
}

// ---------------------------------------------------------------------------
// Pass A: conv + pool + PReLU-split integer stats; STOREP=1 also stores the
// pooled pre-PReLU p (i16, exact range +-448) COALESCED via a hi-half swap.
//
// Conv core mapping [R3/R6-proven]:
//   A[m=pos][k=c]  : lane row = q0 + (lane&31) + kk, 16B at hi*16 / 32+hi*16
//   B[k=c][n=cout] : wk+0=(kb0,n0) +32=(kb1,n0) +2048=(kb0,n1) +2080=(kb1,n1)
//   C/D            : col(lane&31)=cout, row=(reg&3)+8*(reg>>2)+4*(lane>>5)
//
// Coalesced p-store derivation (R8): v[r] = max(acc[2r],acc[2r+1]) sits at
// pooled row prow(r,hi) = (r&1)+4*(r>>1)+2*hi, i.e. lane hi=0 holds prows
// {0,1,4,5,8,9,12,13}, hi=1 holds {2,3,6,7,10,11,14,15}.  Target: lane hi
// stores prows [8*hi, 8*hi+8).  hi=0 needs partner's r0..r3 (= prows 2,3,6,7);
// hi=1 needs partner's r4..r7 (= prows 8,9,12,13).  So each lane SENDS
// (hi ? pk(v0,v1),pk(v2,v3) : pk(v4,v5),pk(v6,v7)) through __shfl_xor(.,32)
// and builds:  hi=0: [own01, q0, own23, q1]  (q = partner's pk(v0,v1)/pk(v2,v3))
//              hi=1: [q0, own45, q1, own67]  (q = partner's pk(v4,v5)/pk(v6,v7))
// then one 16-B store at row base + lp0 + 8*hi (byte off lp0*2+16*hi, 16-B
// aligned since lp0 % 16 == 0).
// ---------------------------------------------------------------------------
template<int STOREP>
__global__ __launch_bounds__(256, 4) void conv_stats_kernel(
    const char* __restrict__ sx, const char* __restrict__ pwb,
    u64* __restrict__ stats, short* __restrict__ pstore, int b_base)
{
    const int tid  = threadIdx.x;
    const int lane = tid & 63;
    const int w    = tid >> 6;         // wave 0..3
    const int ngrp = w & 1;            // co base = ngrp*64
    const int mgrp = w >> 1;           // position half
    const int col  = lane & 31;
    const int hi   = lane >> 5;
    const int bl   = blockIdx.y;
    const int mchunk = blockIdx.x;     // 0..15 (256 positions each)

    const char* sxb = sx + (size_t)bl * LPAD * 64;
    const char* wb0 = pwb + (size_t)((ngrp * 64 + col) * 64) + hi * 16;

    const int gb = b_base + bl;
    short* prow0 = STOREP ? (pstore + ((size_t)gb * COUT + ngrp * 64 + col) * LPOOL)
                          : (short*)nullptr;
    short* prow1 = STOREP ? (prow0 + (size_t)32 * LPOOL) : (short*)nullptr;

    int sp0=0, sn0=0, qp0=0, qn0=0, sp1=0, sn1=0, qp1=0, qn1=0;

    for (int mt = 0; mt < 4; ++mt) {
        const int q0 = mchunk * 256 + mgrp * 128 + mt * 32;
        i32x16 acc0 = ACC_ZERO, acc1 = ACC_ZERO;
        #pragma unroll
        for (int kk = 0; kk < KW; ++kk) {
            const char* ar = sxb + (size_t)(q0 + col + kk) * 64;
            i32x4 x0 = *(const i32x4*)(ar + hi * 16);
            i32x4 x1 = *(const i32x4*)(ar + 32 + hi * 16);
            const char* wk = wb0 + (size_t)kk * (COUT * 64);
            i32x4 w00 = *(const i32x4*)(wk);             // kb0,n0
            i32x4 w01 = *(const i32x4*)(wk + 32);        // kb1,n0
            i32x4 w10 = *(const i32x4*)(wk + 2048);      // kb0,n1
            i32x4 w11 = *(const i32x4*)(wk + 2048 + 32); // kb1,n1
            acc0 = __builtin_amdgcn_mfma_i32_32x32x32_i8(x0, w00, acc0, 0, 0, 0);
            acc0 = __builtin_amdgcn_mfma_i32_32x32x32_i8(x1, w01, acc0, 0, 0, 0);
            acc1 = __builtin_amdgcn_mfma_i32_32x32x32_i8(x0, w10, acc1, 0, 0, 0);
            acc1 = __builtin_amdgcn_mfma_i32_32x32x32_i8(x1, w11, acc1, 0, 0, 0);
        }

        int v0[8], v1[8];
        #pragma unroll
        for (int r = 0; r < 8; ++r) {
            v0[r] = acc0[2*r] > acc0[2*r+1] ? acc0[2*r] : acc0[2*r+1];
            v1[r] = acc1[2*r] > acc1[2*r+1] ? acc1[2*r] : acc1[2*r+1];
        }
        #pragma unroll
        for (int r = 0; r < 8; ++r) {
            int p = v0[r], q = p * p;
            bool pos = p > 0;
            sp0 += pos ? p : 0;  sn0 += pos ? 0 : p;
            qp0 += pos ? q : 0;  qn0 += pos ? 0 : q;
            int p1 = v1[r], q1 = p1 * p1;
            bool pos1 = p1 > 0;
            sp1 += pos1 ? p1 : 0;  sn1 += pos1 ? 0 : p1;
            qp1 += pos1 ? q1 : 0;  qn1 += pos1 ? 0 : q1;
        }

        if (STOREP) {
            const int lp0 = q0 >> 1;
            // chain 0
            {
                int own01 = pk16(v0[0], v0[1]), own23 = pk16(v0[2], v0[3]);
                int own45 = pk16(v0[4], v0[5]), own67 = pk16(v0[6], v0[7]);
                int s0 = hi ? own01 : own45;
                int s1 = hi ? own23 : own67;
                int r0 = __shfl_xor(s0, 32);
                int r1 = __shfl_xor(s1, 32);
                i32x4 ov;
                ov[0] = hi ? r0 : own01;
                ov[1] = hi ? own45 : r0;
                ov[2] = hi ? r1 : own23;
                ov[3] = hi ? own67 : r1;
                *(i32x4*)(prow0 + lp0 + 8 * hi) = ov;
            }
            // chain 1
            {
                int own01 = pk16(v1[0], v1[1]), own23 = pk16(v1[2], v1[3]);
                int own45 = pk16(v1[4], v1[5]), own67 = pk16(v1[6], v1[7]);
                int s0 = hi ? own01 : own45;
                int s1 = hi ? own23 : own67;
                int r0 = __shfl_xor(s0, 32);
                int r1 = __shfl_xor(s1, 32);
                i32x4 ov;
                ov[0] = hi ? r0 : own01;
                ov[1] = hi ? own45 : r0;
                ov[2] = hi ? r1 : own23;
                ov[3] = hi ? own67 : r1;
                *(i32x4*)(prow1 + lp0 + 8 * hi) = ov;
            }
        }
    }

    sp0 += __shfl_xor(sp0, 32);  sn0 += __shfl_xor(sn0, 32);
    qp0 += __shfl_xor(qp0, 32);  qn0 += __shfl_xor(qn0, 32);
    sp1 += __shfl_xor(sp1, 32);  sn1 += __shfl_xor(sn1, 32);
    qp1 += __shfl_xor(qp1, 32);  qn1 += __shfl_xor(qn1, 32);

    if (hi == 0) {
        const int bkt = gb & (NBUCKET - 1);
        u64* s0 = stats + (size_t)(bkt * COUT + ngrp * 64 + col) * 4;
        atomicAdd(&s0[0], (u64)(long long)sp0);
        atomicAdd(&s0[1], (u64)(long long)sn0);
        atomicAdd(&s0[2], (u64)(long long)qp0);
        atomicAdd(&s0[3], (u64)(long long)qn0);
        u64* s1 = stats + (size_t)(bkt * COUT + ngrp * 64 + 32 + col) * 4;
        atomicAdd(&s1[0], (u64)(long long)sp1);
        atomicAdd(&s1[1], (u64)(long long)sn1);
        atomicAdd(&s1[2], (u64)(long long)qp1);
        atomicAdd(&s1[3], (u64)(long long)qn1);
    }
}

// ---------------------------------------------------------------------------
// finalize: sum buckets, exact integer sums -> BN scale/shift.  [R3-proven]
// ---------------------------------------------------------------------------
__global__ void finalize_kernel(const u64* __restrict__ stats,
                                const float* __restrict__ alpha,
                                const float* __restrict__ gamma,
                                const float* __restrict__ beta,
                                float2* __restrict__ scsh)
{
    int c = threadIdx.x;
    if (c >= COUT) return;
    long long s[4] = {0, 0, 0, 0};
    for (int bk = 0; bk < NBUCKET; ++bk)
        #pragma unroll
        for (int i = 0; i < 4; ++i)
            s[i] += (long long)stats[(size_t)(bk * COUT + c) * 4 + i];
    double a    = (double)alpha[0];
    double N    = (double)NPERCH;
    double sum  = (double)s[0] + a * (double)s[1];
    double ssq  = (double)s[2] + a * a * (double)s[3];
    double mean = sum / N;
    double var  = ssq / N - mean * mean;
    double inv  = 1.0 / sqrt(var + 1e-5);
    double g    = (double)gamma[c];
    scsh[c] = make_float2((float)(g * inv),
                          (float)((double)beta[c] - mean * g * inv));
}

// ---------------------------------------------------------------------------
// bn_write: streaming p(i16) -> PReLU -> BN affine -> out(fp32).  [R7-proven]
// ---------------------------------------------------------------------------
__global__ __launch_bounds__(256) void bn_write_kernel(
    const short* __restrict__ p, const float2* __restrict__ scsh,
    const float* __restrict__ alpha, float* __restrict__ out)
{
    const float a = alpha[0];
    const size_t i = ((size_t)blockIdx.x * 256 + threadIdx.x) * 8;
    const int co = (int)((i >> 11) & (COUT - 1));     // LPOOL = 2048
    const float2 ss = scsh[co];
    const s16x8 v = *(const s16x8*)(p + i);
    float4 o0, o1;
    #pragma unroll
    for (int j = 0; j < 4; ++j) {
        float pv = (float)v[j];
        float y = (pv > 0.0f) ? pv : a * pv;
        ((float*)&o0)[j] = fmaf(y, ss.x, ss.y);
    }
    #pragma unroll
    for (int j = 0; j < 4; ++j) {
        float pv = (float)v[4 + j];
        float y = (pv > 0.0f) ? pv : a * pv;
        ((float*)&o1)[j] = fmaf(y, ss.x, ss.y);
    }
    *(float4*)(out + i)     = o0;
    *(float4*)(out + i + 4) = o1;
}

// ---------------------------------------------------------------------------
// Fallback pass B [R6-proven verbatim]: conv + pool + PReLU + BN, fp32 out.
// Used only when ws_size cannot hold sx + p.
// ---------------------------------------------------------------------------
__global__ __launch_bounds__(256, 2) void conv_write_kernel(
    const char* __restrict__ sx, const char* __restrict__ pwb,
    const float2* __restrict__ scsh, const float* __restrict__ alpha,
    float* __restrict__ out, int b_base)
{
    const int tid  = threadIdx.x;
    const int lane = tid & 63;
    const int w    = tid >> 6;
    const int ngrp = w & 1;
    const int mgrp = w >> 1;
    const int col  = lane & 31;
    const int hi   = lane >> 5;
    const int bl   = blockIdx.y;
    const int mchunk = blockIdx.x;

    const char* sxb = sx + (size_t)bl * LPAD * 64;
    const char* wb0 = pwb + (size_t)((ngrp * 64 + col) * 64) + hi * 16;

    const float a = alpha[0];
    const float2 ss0 = scsh[ngrp * 64 + col];
    const float2 ss1 = scsh[ngrp * 64 + 32 + col];
    const int gb = b_base + bl;
    float* orow0 = out + ((size_t)gb * COUT + ngrp * 64 + col) * LPOOL;
    float* orow1 = orow0 + (size_t)32 * LPOOL;

    for (int mt = 0; mt < 4; ++mt) {
        const int q0 = mchunk * 256 + mgrp * 128 + mt * 32;
        i32x16 a00 = ACC_ZERO, a01 = ACC_ZERO, a10 = ACC_ZERO, a11 = ACC_ZERO;
        #pragma unroll
        for (int kk = 0; kk < KW; ++kk) {
            const char* ar = sxb + (size_t)(q0 + col + kk) * 64;
            i32x4 x0 = *(const i32x4*)(ar + hi * 16);
            i32x4 x1 = *(const i32x4*)(ar + 32 + hi * 16);
            const char* wk = wb0 + (size_t)kk * (COUT * 64);
            i32x4 w00 = *(const i32x4*)(wk);
            i32x4 w01 = *(const i32x4*)(wk + 32);
            i32x4 w10 = *(const i32x4*)(wk + 2048);
            i32x4 w11 = *(const i32x4*)(wk + 2048 + 32);
            a00 = __builtin_amdgcn_mfma_i32_32x32x32_i8(x0, w00, a00, 0, 0, 0);
            a01 = __builtin_amdgcn_mfma_i32_32x32x32_i8(x1, w01, a01, 0, 0, 0);
            a10 = __builtin_amdgcn_mfma_i32_32x32x32_i8(x0, w10, a10, 0, 0, 0);
            a11 = __builtin_amdgcn_mfma_i32_32x32x32_i8(x1, w11, a11, 0, 0, 0);
        }
        i32x16 acc0 = a00 + a01;
        i32x16 acc1 = a10 + a11;
        const int lp0 = q0 >> 1;
        #pragma unroll
        for (int r = 0; r < 8; ++r) {
            const int prow = (r & 1) + 4 * (r >> 1) + 2 * hi;
            int p = acc0[2*r] > acc0[2*r+1] ? acc0[2*r] : acc0[2*r+1];
            float y = (p > 0) ? (float)p : a * (float)p;
            orow0[lp0 + prow] = fmaf(y, ss0.x, ss0.y);
            p = acc1[2*r] > acc1[2*r+1] ? acc1[2*r] : acc1[2*r+1];
            y = (p > 0) ? (float)p : a * (float)p;
            orow1[lp0 + prow] = fmaf(y, ss1.x, ss1.y);
        }
    }
}

// ---------------------------------------------------------------------------
extern "C" void kernel_launch(void* const* d_in, const int* in_sizes, int n_in,
                              void* d_out, int out_size, void* d_ws, size_t ws_size,
                              hipStream_t stream)
{
    const float* x     = (const float*)d_in[0];
    const float* W     = (const float*)d_in[1];
    const float* alpha = (const float*)d_in[2];
    const float* gamma = (const float*)d_in[3];
    const float* beta  = (const float*)d_in[4];
    float* out = (float*)d_out;

    const size_t sx_sz    = (size_t)BATCH * LPAD * 64;        // 67,207,168
    const size_t p_sz     = (size_t)BATCH * COUT * LPOOL * 2; // 134,217,728
    const size_t pwb_sz   = (size_t)KW * COUT * CIN;          // 57,344
    const size_t stats_sz = (size_t)NBUCKET * COUT * 4 * 8;   // 262,144
    const size_t scsh_sz  = (size_t)COUT * 8;
    const size_t fixed    = pwb_sz + stats_sz + scsh_sz + 4096;

    char* ws = (char*)d_ws;

    if (ws_size >= sx_sz + p_sz + fixed) {
        // ------------------- fast path: store pooled p -------------------
        char* sx = ws;
        size_t off = (sx_sz + 255) & ~(size_t)255;
        short* p = (short*)(ws + off);       off = (off + p_sz + 255) & ~(size_t)255;
        char* pwb = ws + off;                off = (off + pwb_sz + 255) & ~(size_t)255;
        u64* stats = (u64*)(ws + off);       off = (off + stats_sz + 255) & ~(size_t)255;
        float2* scsh = (float2*)(ws + off);

        hipMemsetAsync(stats, 0, stats_sz, stream);
        pack_w_kernel<<<dim3(224), 256, 0, stream>>>(W, pwb);
        pack_x_kernel<<<dim3(16, BATCH), 256, 0, stream>>>(x, sx, 0);
        conv_stats_kernel<1><<<dim3(16, BATCH), 256, 0, stream>>>(sx, pwb, stats, p, 0);
        finalize_kernel<<<dim3(1), 128, 0, stream>>>(stats, alpha, gamma, beta, scsh);
        bn_write_kernel<<<dim3(32768), 256, 0, stream>>>(p, scsh, alpha, out);
        return;
    }

    // ------------------- fallback: R6 two-conv path -------------------
    const size_t PER_B = (size_t)LPAD * 64;
    int nb = BATCH;
    if (ws_size < PER_B * BATCH + fixed) {
        size_t avail = (ws_size > fixed) ? (ws_size - fixed) : PER_B;
        nb = (int)(avail / PER_B);
        if (nb < 1) nb = 1;
        if (nb > BATCH) nb = BATCH;
    }

    char* sx = ws;
    size_t off = ((PER_B * (size_t)nb) + 255) & ~(size_t)255;
    char* pwb = ws + off;               off = (off + pwb_sz + 255) & ~(size_t)255;
    u64* stats = (u64*)(ws + off);      off = (off + stats_sz + 255) & ~(size_t)255;
    float2* scsh = (float2*)(ws + off);

    hipMemsetAsync(stats, 0, stats_sz, stream);
    pack_w_kernel<<<dim3(224), 256, 0, stream>>>(W, pwb);

    for (int b0 = 0; b0 < BATCH; b0 += nb) {
        int n = (BATCH - b0 < nb) ? (BATCH - b0) : nb;
        pack_x_kernel<<<dim3(16, n), 256, 0, stream>>>(x, sx, b0);
        conv_stats_kernel<0><<<dim3(16, n), 256, 0, stream>>>(sx, pwb, stats, nullptr, b0);
    }
    finalize_kernel<<<dim3(1), 128, 0, stream>>>(stats, alpha, gamma, beta, scsh);

    if (nb == BATCH) {
        conv_write_kernel<<<dim3(16, BATCH), 256, 0, stream>>>(sx, pwb, scsh, alpha, out, 0);
    } else {
        for (int b0 = 0; b0 < BATCH; b0 += nb) {
            int n = (BATCH - b0 < nb) ? (BATCH - b0) : nb;
            pack_x_kernel<<<dim3(16, n), 256, 0, stream>>>(x, sx, b0);
            conv_write_kernel<<<dim3(16, n), 256, 0, stream>>>(sx, pwb, scsh, alpha, out, b0);
        }
    }
}

// Round 9
// 365.208 us; speedup vs baseline: 1.2965x; 1.2965x over previous
//
#include <hip/hip_runtime.h>
#include <stdint.h>

#define BATCH 256
#define CIN   64
#define LIN   4096
#define PADN  3
#define LPAD  4102            /* 4096 + 2*3 */
#define COUT  128
#define KW    7
#define LPOOL 2048
#define NBUCKET 64
#define NPERCH (256LL * 2048LL)

typedef unsigned long long u64;
typedef __attribute__((ext_vector_type(4)))  int i32x4;
typedef __attribute__((ext_vector_type(16))) int i32x16;
typedef __attribute__((ext_vector_type(8)))  short s16x8;

#define ACC_ZERO {0,0,0,0,0,0,0,0,0,0,0,0,0,0,0,0}

static __device__ __forceinline__ int pk16(int a, int b)
{
    return (a & 0xFFFF) | (b << 16);   // low short = first value
}

// ---------------------------------------------------------------------------
// pack_x: x[b][c][l] fp32 -> sx[b_local][l+3][c] i8 sign (+1/-1/0).
// Pad rows (0..2, 4099..4101) = -1 (sign of pad value -1.0).  [R3-proven]
// ---------------------------------------------------------------------------
__global__ __launch_bounds__(256) void pack_x_kernel(const float* __restrict__ x,
                                                     char* __restrict__ sx,
                                                     int b_base)
{
    const int t  = threadIdx.x;
    const int lt = blockIdx.x;            // 16 tiles of 256 positions
    const int bl = blockIdx.y;            // local batch index in chunk
    const int b  = b_base + bl;
    const int l  = lt * 256 + t;
    const float* xb = x + (size_t)b * CIN * LIN + l;

    int o[16];
    #pragma unroll
    for (int cw = 0; cw < 16; ++cw) {
        unsigned wv = 0;
        #pragma unroll
        for (int j = 0; j < 4; ++j) {
            float v = xb[(size_t)(cw * 4 + j) * LIN];
            unsigned s = (v > 0.0f) ? 1u : ((v < 0.0f) ? 0xFFu : 0u);
            wv |= s << (8 * j);
        }
        o[cw] = (int)wv;
    }
    i32x4* dst = (i32x4*)(sx + ((size_t)bl * LPAD + (l + PADN)) * 64);
    dst[0] = (i32x4){o[0],  o[1],  o[2],  o[3]};
    dst[1] = (i32x4){o[4],  o[5],  o[6],  o[7]};
    dst[2] = (i32x4){o[8],  o[9],  o[10], o[11]};
    dst[3] = (i32x4){o[12], o[13], o[14], o[15]};

    const i32x4 ff = (i32x4){-1, -1, -1, -1};   // bytes 0xFF = sign(-1)
    if (lt == 0 && t < PADN) {
        i32x4* pd = (i32x4*)(sx + ((size_t)bl * LPAD + t) * 64);
        pd[0] = ff; pd[1] = ff; pd[2] = ff; pd[3] = ff;
    }
    if (lt == 15 && t < PADN) {
        i32x4* pd = (i32x4*)(sx + ((size_t)bl * LPAD + (LIN + PADN) + t) * 64);
        pd[0] = ff; pd[1] = ff; pd[2] = ff; pd[3] = ff;
    }
}

// ---------------------------------------------------------------------------
// pack_w: W[co][c][kk] fp32 -> pwb[kk][co][c] i8 sign.  [R3-proven]
// ---------------------------------------------------------------------------
__global__ __launch_bounds__(256) void pack_w_kernel(const float* __restrict__ w,
                                                     char* __restrict__ pwb)
{
    int idx = blockIdx.x * 256 + threadIdx.x;     // [0, 7*128*64)
    if (idx >= KW * COUT * CIN) return;
    int kk = idx >> 13;
    int co = (idx >> 6) & 127;
    int c  = idx & 63;
    float v = w[((size_t)co * CIN + c) * KW + kk];
    pwb[idx] = (char)((v > 0.0f) ? 1 : ((v < 0.0f) ? -1 : 0));
}

// ---------------------------------------------------------------------------
// Pass A [R3/R7-proven core]: conv + pool + PReLU-split integer stats;
// STOREP=1 stores pooled pre-PReLU p (i16) in MFMA-NATIVE layout:
//   p[((((b*16+mchunk)*4+w)*2+chain)*4+mt)*64 + lane] : s16x8 (16B/lane)
//   lane's 8 shorts = v[r], r=0..7, packed (v0,v1),(v2,v3),(v4,v5),(v6,v7).
// Per store instruction: 64 lanes x 16B CONTIGUOUS (1KB) -> zero write
// amplification, zero shuffles.  Semantics of element (w,chain,mt,lane,r):
//   cout = (w&1)*64 + chain*32 + (lane&31)
//   pooled pos = mchunk*128 + (w>>1)*64 + mt*16 + (r&1)+4*(r>>1)+2*(lane>>5)
// (prow formula = R3-proven C/D row mapping / 2.)
// ---------------------------------------------------------------------------
template<int STOREP>
__global__ __launch_bounds__(256, 3) void conv_stats_kernel(
    const char* __restrict__ sx, const char* __restrict__ pwb,
    u64* __restrict__ stats, short* __restrict__ pstore, int b_base)
{
    const int tid  = threadIdx.x;
    const int lane = tid & 63;
    const int w    = tid >> 6;         // wave 0..3
    const int ngrp = w & 1;            // co base = ngrp*64
    const int mgrp = w >> 1;           // position half
    const int col  = lane & 31;
    const int hi   = lane >> 5;
    const int bl   = blockIdx.y;
    const int mchunk = blockIdx.x;     // 0..15 (256 positions each)

    const char* sxb = sx + (size_t)bl * LPAD * 64;
    const char* wb0 = pwb + (size_t)((ngrp * 64 + col) * 64) + hi * 16;

    const int gb = b_base + bl;
    // native-layout base for this wave: ...(b,mchunk,w) fixed, (chain,mt,lane) vary
    short* pwave = STOREP
        ? (pstore + ((((size_t)gb * 16 + mchunk) * 4 + w) * 2) * 4 * 64 * 8)
        : (short*)nullptr;

    int sp0=0, sn0=0, qp0=0, qn0=0, sp1=0, sn1=0, qp1=0, qn1=0;

    for (int mt = 0; mt < 4; ++mt) {
        const int q0 = mchunk * 256 + mgrp * 128 + mt * 32;
        i32x16 acc0 = ACC_ZERO, acc1 = ACC_ZERO;
        #pragma unroll
        for (int kk = 0; kk < KW; ++kk) {
            const char* ar = sxb + (size_t)(q0 + col + kk) * 64;
            i32x4 x0 = *(const i32x4*)(ar + hi * 16);
            i32x4 x1 = *(const i32x4*)(ar + 32 + hi * 16);
            const char* wk = wb0 + (size_t)kk * (COUT * 64);
            i32x4 w00 = *(const i32x4*)(wk);             // kb0,n0
            i32x4 w01 = *(const i32x4*)(wk + 32);        // kb1,n0
            i32x4 w10 = *(const i32x4*)(wk + 2048);      // kb0,n1
            i32x4 w11 = *(const i32x4*)(wk + 2048 + 32); // kb1,n1
            acc0 = __builtin_amdgcn_mfma_i32_32x32x32_i8(x0, w00, acc0, 0, 0, 0);
            acc0 = __builtin_amdgcn_mfma_i32_32x32x32_i8(x1, w01, acc0, 0, 0, 0);
            acc1 = __builtin_amdgcn_mfma_i32_32x32x32_i8(x0, w10, acc1, 0, 0, 0);
            acc1 = __builtin_amdgcn_mfma_i32_32x32x32_i8(x1, w11, acc1, 0, 0, 0);
        }

        int v0[8], v1[8];
        #pragma unroll
        for (int r = 0; r < 8; ++r) {
            v0[r] = acc0[2*r] > acc0[2*r+1] ? acc0[2*r] : acc0[2*r+1];
            v1[r] = acc1[2*r] > acc1[2*r+1] ? acc1[2*r] : acc1[2*r+1];
        }
        #pragma unroll
        for (int r = 0; r < 8; ++r) {
            int p = v0[r], q = p * p;
            bool pos = p > 0;
            sp0 += pos ? p : 0;  sn0 += pos ? 0 : p;
            qp0 += pos ? q : 0;  qn0 += pos ? 0 : q;
            int p1 = v1[r], q1 = p1 * p1;
            bool pos1 = p1 > 0;
            sp1 += pos1 ? p1 : 0;  sn1 += pos1 ? 0 : p1;
            qp1 += pos1 ? q1 : 0;  qn1 += pos1 ? 0 : q1;
        }

        if (STOREP) {
            // chain 0: offset ((0*4 + mt)*64 + lane)*8 shorts
            i32x4 o0 = (i32x4){pk16(v0[0], v0[1]), pk16(v0[2], v0[3]),
                               pk16(v0[4], v0[5]), pk16(v0[6], v0[7])};
            *(i32x4*)(pwave + ((size_t)(mt * 64 + lane)) * 8) = o0;
            // chain 1: offset ((1*4 + mt)*64 + lane)*8 shorts
            i32x4 o1 = (i32x4){pk16(v1[0], v1[1]), pk16(v1[2], v1[3]),
                               pk16(v1[4], v1[5]), pk16(v1[6], v1[7])};
            *(i32x4*)(pwave + ((size_t)((4 + mt) * 64 + lane)) * 8) = o1;
        }
    }

    sp0 += __shfl_xor(sp0, 32);  sn0 += __shfl_xor(sn0, 32);
    qp0 += __shfl_xor(qp0, 32);  qn0 += __shfl_xor(qn0, 32);
    sp1 += __shfl_xor(sp1, 32);  sn1 += __shfl_xor(sn1, 32);
    qp1 += __shfl_xor(qp1, 32);  qn1 += __shfl_xor(qn1, 32);

    if (hi == 0) {
        const int bkt = gb & (NBUCKET - 1);
        u64* s0 = stats + (size_t)(bkt * COUT + ngrp * 64 + col) * 4;
        atomicAdd(&s0[0], (u64)(long long)sp0);
        atomicAdd(&s0[1], (u64)(long long)sn0);
        atomicAdd(&s0[2], (u64)(long long)qp0);
        atomicAdd(&s0[3], (u64)(long long)qn0);
        u64* s1 = stats + (size_t)(bkt * COUT + ngrp * 64 + 32 + col) * 4;
        atomicAdd(&s1[0], (u64)(long long)sp1);
        atomicAdd(&s1[1], (u64)(long long)sn1);
        atomicAdd(&s1[2], (u64)(long long)qp1);
        atomicAdd(&s1[3], (u64)(long long)qn1);
    }
}

// ---------------------------------------------------------------------------
// finalize: sum buckets, exact integer sums -> BN scale/shift.  [R3-proven]
// ---------------------------------------------------------------------------
__global__ void finalize_kernel(const u64* __restrict__ stats,
                                const float* __restrict__ alpha,
                                const float* __restrict__ gamma,
                                const float* __restrict__ beta,
                                float2* __restrict__ scsh)
{
    int c = threadIdx.x;
    if (c >= COUT) return;
    long long s[4] = {0, 0, 0, 0};
    for (int bk = 0; bk < NBUCKET; ++bk)
        #pragma unroll
        for (int i = 0; i < 4; ++i)
            s[i] += (long long)stats[(size_t)(bk * COUT + c) * 4 + i];
    double a    = (double)alpha[0];
    double N    = (double)NPERCH;
    double sum  = (double)s[0] + a * (double)s[1];
    double ssq  = (double)s[2] + a * a * (double)s[3];
    double mean = sum / N;
    double var  = ssq / N - mean * mean;
    double inv  = 1.0 / sqrt(var + 1e-5);
    double g    = (double)gamma[c];
    scsh[c] = make_float2((float)(g * inv),
                          (float)((double)beta[c] - mean * g * inv));
}

// ---------------------------------------------------------------------------
// bn_write: gather p from MFMA-native layout, PReLU + BN affine, fp32 out.
// Block = (mchunk, b); 256 threads x 4 iters cover 128 couts x 8 segments.
// Work item (cout, seg): seg = mgrp*4+mt selects 16 pooled positions.
//   w = mgrp*2 + (cout>>6); chain = (cout>>5)&1; col = cout&31.
//   blk0 = lane (hi=0,col) 8 shorts -> prows {0,1,4,5,8,9,12,13}
//   blk1 = lane (hi=1,col) 8 shorts -> prows {2,3,6,7,10,11,14,15}
//   out positions 4q+{0,1,2,3} = b0[2q], b0[2q+1], b1[2q], b1[2q+1].
// Every fetched p line is fully consumed by this block -> HBM-exact reads;
// out writes are 64B-contiguous per thread.
// ---------------------------------------------------------------------------
__global__ __launch_bounds__(256) void bn_write_kernel(
    const short* __restrict__ p, const float2* __restrict__ scsh,
    const float* __restrict__ alpha, float* __restrict__ out)
{
    const int mchunk = blockIdx.x;
    const int b      = blockIdx.y;
    const float a = alpha[0];
    const short* ptile = p + (((size_t)b * 16 + mchunk) * 4) * 2 * 4 * 64 * 8;

    #pragma unroll
    for (int i = 0; i < 4; ++i) {
        const int item = i * 256 + threadIdx.x;   // [0,1024): cout*8 + seg
        const int cout = item >> 3;
        const int seg  = item & 7;
        const int mgrp = seg >> 2, mt = seg & 3;
        const int wv   = mgrp * 2 + (cout >> 6);
        const int chain = (cout >> 5) & 1;
        const int col   = cout & 31;

        const short* base = ptile + ((size_t)((wv * 2 + chain) * 4 + mt) * 64) * 8;
        s16x8 b0 = *(const s16x8*)(base + (size_t)col * 8);
        s16x8 b1 = *(const s16x8*)(base + (size_t)(32 + col) * 8);

        const float2 ss = scsh[cout];
        float* op = out + ((size_t)b * COUT + cout) * LPOOL + mchunk * 128 + seg * 16;
        #pragma unroll
        for (int q = 0; q < 4; ++q) {
            float4 o;
            float pv, y;
            pv = (float)b0[2*q];     y = (pv > 0.0f) ? pv : a * pv;  o.x = fmaf(y, ss.x, ss.y);
            pv = (float)b0[2*q + 1]; y = (pv > 0.0f) ? pv : a * pv;  o.y = fmaf(y, ss.x, ss.y);
            pv = (float)b1[2*q];     y = (pv > 0.0f) ? pv : a * pv;  o.z = fmaf(y, ss.x, ss.y);
            pv = (float)b1[2*q + 1]; y = (pv > 0.0f) ? pv : a * pv;  o.w = fmaf(y, ss.x, ss.y);
            *(float4*)(op + q * 4) = o;
        }
    }
}

// ---------------------------------------------------------------------------
// Fallback pass B [R6-proven verbatim]: conv + pool + PReLU + BN, fp32 out.
// Used only when ws_size cannot hold sx + p.
// ---------------------------------------------------------------------------
__global__ __launch_bounds__(256, 2) void conv_write_kernel(
    const char* __restrict__ sx, const char* __restrict__ pwb,
    const float2* __restrict__ scsh, const float* __restrict__ alpha,
    float* __restrict__ out, int b_base)
{
    const int tid  = threadIdx.x;
    const int lane = tid & 63;
    const int w    = tid >> 6;
    const int ngrp = w & 1;
    const int mgrp = w >> 1;
    const int col  = lane & 31;
    const int hi   = lane >> 5;
    const int bl   = blockIdx.y;
    const int mchunk = blockIdx.x;

    const char* sxb = sx + (size_t)bl * LPAD * 64;
    const char* wb0 = pwb + (size_t)((ngrp * 64 + col) * 64) + hi * 16;

    const float a = alpha[0];
    const float2 ss0 = scsh[ngrp * 64 + col];
    const float2 ss1 = scsh[ngrp * 64 + 32 + col];
    const int gb = b_base + bl;
    float* orow0 = out + ((size_t)gb * COUT + ngrp * 64 + col) * LPOOL;
    float* orow1 = orow0 + (size_t)32 * LPOOL;

    for (int mt = 0; mt < 4; ++mt) {
        const int q0 = mchunk * 256 + mgrp * 128 + mt * 32;
        i32x16 a00 = ACC_ZERO, a01 = ACC_ZERO, a10 = ACC_ZERO, a11 = ACC_ZERO;
        #pragma unroll
        for (int kk = 0; kk < KW; ++kk) {
            const char* ar = sxb + (size_t)(q0 + col + kk) * 64;
            i32x4 x0 = *(const i32x4*)(ar + hi * 16);
            i32x4 x1 = *(const i32x4*)(ar + 32 + hi * 16);
            const char* wk = wb0 + (size_t)kk * (COUT * 64);
            i32x4 w00 = *(const i32x4*)(wk);
            i32x4 w01 = *(const i32x4*)(wk + 32);
            i32x4 w10 = *(const i32x4*)(wk + 2048);
            i32x4 w11 = *(const i32x4*)(wk + 2048 + 32);
            a00 = __builtin_amdgcn_mfma_i32_32x32x32_i8(x0, w00, a00, 0, 0, 0);
            a01 = __builtin_amdgcn_mfma_i32_32x32x32_i8(x1, w01, a01, 0, 0, 0);
            a10 = __builtin_amdgcn_mfma_i32_32x32x32_i8(x0, w10, a10, 0, 0, 0);
            a11 = __builtin_amdgcn_mfma_i32_32x32x32_i8(x1, w11, a11, 0, 0, 0);
        }
        i32x16 acc0 = a00 + a01;
        i32x16 acc1 = a10 + a11;
        const int lp0 = q0 >> 1;
        #pragma unroll
        for (int r = 0; r < 8; ++r) {
            const int prow = (r & 1) + 4 * (r >> 1) + 2 * hi;
            int p = acc0[2*r] > acc0[2*r+1] ? acc0[2*r] : acc0[2*r+1];
            float y = (p > 0) ? (float)p : a * (float)p;
            orow0[lp0 + prow] = fmaf(y, ss0.x, ss0.y);
            p = acc1[2*r] > acc1[2*r+1] ? acc1[2*r] : acc1[2*r+1];
            y = (p > 0) ? (float)p : a * (float)p;
            orow1[lp0 + prow] = fmaf(y, ss1.x, ss1.y);
        }
    }
}

// ---------------------------------------------------------------------------
extern "C" void kernel_launch(void* const* d_in, const int* in_sizes, int n_in,
                              void* d_out, int out_size, void* d_ws, size_t ws_size,
                              hipStream_t stream)
{
    const float* x     = (const float*)d_in[0];
    const float* W     = (const float*)d_in[1];
    const float* alpha = (const float*)d_in[2];
    const float* gamma = (const float*)d_in[3];
    const float* beta  = (const float*)d_in[4];
    float* out = (float*)d_out;

    const size_t sx_sz    = (size_t)BATCH * LPAD * 64;        // 67,207,168
    const size_t p_sz     = (size_t)BATCH * COUT * LPOOL * 2; // 134,217,728
    const size_t pwb_sz   = (size_t)KW * COUT * CIN;          // 57,344
    const size_t stats_sz = (size_t)NBUCKET * COUT * 4 * 8;   // 262,144
    const size_t scsh_sz  = (size_t)COUT * 8;
    const size_t fixed    = pwb_sz + stats_sz + scsh_sz + 4096;

    char* ws = (char*)d_ws;

    if (ws_size >= sx_sz + p_sz + fixed) {
        // ------------------- fast path: store pooled p -------------------
        char* sx = ws;
        size_t off = (sx_sz + 255) & ~(size_t)255;
        short* p = (short*)(ws + off);       off = (off + p_sz + 255) & ~(size_t)255;
        char* pwb = ws + off;                off = (off + pwb_sz + 255) & ~(size_t)255;
        u64* stats = (u64*)(ws + off);       off = (off + stats_sz + 255) & ~(size_t)255;
        float2* scsh = (float2*)(ws + off);

        hipMemsetAsync(stats, 0, stats_sz, stream);
        pack_w_kernel<<<dim3(224), 256, 0, stream>>>(W, pwb);
        pack_x_kernel<<<dim3(16, BATCH), 256, 0, stream>>>(x, sx, 0);
        conv_stats_kernel<1><<<dim3(16, BATCH), 256, 0, stream>>>(sx, pwb, stats, p, 0);
        finalize_kernel<<<dim3(1), 128, 0, stream>>>(stats, alpha, gamma, beta, scsh);
        bn_write_kernel<<<dim3(16, BATCH), 256, 0, stream>>>(p, scsh, alpha, out);
        return;
    }

    // ------------------- fallback: R6 two-conv path -------------------
    const size_t PER_B = (size_t)LPAD * 64;
    int nb = BATCH;
    if (ws_size < PER_B * BATCH + fixed) {
        size_t avail = (ws_size > fixed) ? (ws_size - fixed) : PER_B;
        nb = (int)(avail / PER_B);
        if (nb < 1) nb = 1;
        if (nb > BATCH) nb = BATCH;
    }

    char* sx = ws;
    size_t off = ((PER_B * (size_t)nb) + 255) & ~(size_t)255;
    char* pwb = ws + off;               off = (off + pwb_sz + 255) & ~(size_t)255;
    u64* stats = (u64*)(ws + off);      off = (off + stats_sz + 255) & ~(size_t)255;
    float2* scsh = (float2*)(ws + off);

    hipMemsetAsync(stats, 0, stats_sz, stream);
    pack_w_kernel<<<dim3(224), 256, 0, stream>>>(W, pwb);

    for (int b0 = 0; b0 < BATCH; b0 += nb) {
        int n = (BATCH - b0 < nb) ? (BATCH - b0) : nb;
        pack_x_kernel<<<dim3(16, n), 256, 0, stream>>>(x, sx, b0);
        conv_stats_kernel<0><<<dim3(16, n), 256, 0, stream>>>(sx, pwb, stats, nullptr, b0);
    }
    finalize_kernel<<<dim3(1), 128, 0, stream>>>(stats, alpha, gamma, beta, scsh);

    if (nb == BATCH) {
        conv_write_kernel<<<dim3(16, BATCH), 256, 0, stream>>>(sx, pwb, scsh, alpha, out, 0);
    } else {
        for (int b0 = 0; b0 < BATCH; b0 += nb) {
            int n = (BATCH - b0 < nb) ? (BATCH - b0) : nb;
            pack_x_kernel<<<dim3(16, n), 256, 0, stream>>>(x, sx, b0);
            conv_write_kernel<<<dim3(16, n), 256, 0, stream>>>(sx, pwb, scsh, alpha, out, b0);
        }
    }
}